// Round 6
// baseline (395.571 us; speedup 1.0000x reference)
//
#include <hip/hip_runtime.h>
#include <stdint.h>

typedef __bf16 bf16;
typedef __bf16 bf16x8 __attribute__((ext_vector_type(8)));
typedef __bf16 bf16x4 __attribute__((ext_vector_type(4)));
typedef float  f32x4  __attribute__((ext_vector_type(4)));
typedef short  s16x4  __attribute__((ext_vector_type(4)));
typedef unsigned long long ull;

#define GLOAD16(gptr, lptr)                                                     \
  __builtin_amdgcn_global_load_lds(                                             \
      (const __attribute__((address_space(1))) void*)(gptr),                    \
      (__attribute__((address_space(3))) void*)(lptr), 16, 0, 0)

#define MFMA16(a, b, c) __builtin_amdgcn_mfma_f32_16x16x32_bf16((a), (b), (c), 0, 0, 0)
#define MFMA16K16(a, b, c) __builtin_amdgcn_mfma_f32_16x16x16bf16_1k((a), (b), (c), 0, 0, 0)

static constexpr int B_ = 2, L_ = 2048, NH_ = 16, DH_ = 64;
static constexpr float QSCALE = 0.18033688011112042f;  // 0.125 * log2(e)

// ---------- fused prep: maskbits | fp32->bf16 cvt | weight transpose ----------
// grid.x = 32768 (mask) + 12288 (cvt, 3x4096) + 4096 (wtrans, 4x1024)
__global__ __launch_bounds__(256) void k_prep(const float* __restrict__ q,
                                              const float* __restrict__ k,
                                              const float* __restrict__ v,
                                              const int* __restrict__ mask,
                                              const float* __restrict__ wq,
                                              const float* __restrict__ wk,
                                              const float* __restrict__ wv,
                                              const float* __restrict__ wo,
                                              bf16* __restrict__ X,
                                              bf16* __restrict__ Wt,
                                              ull* __restrict__ mb) {
  __shared__ float t[32][33];
  const int bid = blockIdx.x, tid = threadIdx.x;
  if (bid < 32768) {  // mask int32 -> packed bits
    int tt = bid * 256 + tid;
    ull bal = __ballot(mask[tt] != 0);
    if ((tid & 63) == 0) mb[tt >> 6] = bal;
  } else if (bid < 45056) {  // fp32 -> bf16 x4
    int u = bid - 32768;
    int z = u >> 12, x = u & 4095;
    const float* in = z == 0 ? q : (z == 1 ? k : v);
    bf16* out = X + (size_t)z * 4194304;
    int i = x * 256 + tid;
    const float4 f = ((const float4*)in)[i];
    bf16x4 o = {(bf16)f.x, (bf16)f.y, (bf16)f.z, (bf16)f.w};
    ((bf16x4*)out)[i] = o;
  } else {  // weight fp32 KxN -> bf16 NxK
    int u = bid - 45056;
    int z = u >> 10, rem = u & 1023;
    const float* in = z == 0 ? wq : (z == 1 ? wk : (z == 2 ? wv : wo));
    bf16* out = Wt + (size_t)z * 1048576;
    int bx = (rem & 31) * 32, by = (rem >> 5) * 32;
    int x = tid & 31, y = tid >> 5;
#pragma unroll
    for (int r = 0; r < 4; ++r)
      t[y + r * 8][x] = in[(size_t)(by + y + r * 8) * 1024 + bx + x];
    __syncthreads();
#pragma unroll
    for (int r = 0; r < 4; ++r)
      out[(size_t)(bx + y + r * 8) * 1024 + by + x] = (bf16)t[x][y + r * 8];
  }
}

// ---------- batched 3-proj GEMM: 128x128 tile, BK=32 (R4 config) ----------
// z=0: Q scaled by QSCALE. z=2: V pre-tiled per raw-view head (faithful-bug reshape):
//   h = l>>7, i = (l&127)*16 + (col>>6), d = col&63; Vt[bh][((i>>2)*64 + d)*4 + (i&3)]
__global__ __launch_bounds__(256) void k_gemm3(const bf16* __restrict__ Xb,
                                               const bf16* __restrict__ Wb,
                                               const float* __restrict__ b0,
                                               const float* __restrict__ b1,
                                               const float* __restrict__ b2,
                                               bf16* __restrict__ Ob) {
  const int z = blockIdx.z;
  const bf16* A  = Xb + (size_t)z * 4194304;
  const bf16* Bt = Wb + (size_t)z * 1048576;
  const float* bias = z == 0 ? b0 : (z == 1 ? b1 : b2);
  bf16* C = Ob + (size_t)z * 4194304;
  const int m0 = blockIdx.y * 128, n0 = blockIdx.x * 128;
  __shared__ __align__(16) bf16 As[128 * 32];  // slot(r,c) = r*4 + (c ^ ((r>>1)&3))
  __shared__ __align__(16) bf16 Bs[128 * 32];
  const int tid = threadIdx.x, lane = tid & 63, w = tid >> 6, quad = lane >> 4, l15 = lane & 15;
  const int wm = (w & 1) * 64, wn = (w >> 1) * 64;
  f32x4 acc[4][4] = {};
  for (int kt = 0; kt < 32; ++kt) {
    const int kk = kt * 32;
#pragma unroll
    for (int i = 0; i < 2; ++i) {
      int s = tid + i * 256;
      int r = s >> 2, c = (s & 3) ^ ((r >> 1) & 3);
      GLOAD16(A + (size_t)(m0 + r) * 1024 + kk + c * 8, As + s * 8);
      GLOAD16(Bt + (size_t)(n0 + r) * 1024 + kk + c * 8, Bs + s * 8);
    }
    __syncthreads();
    bf16x8 af[4], bb[4];
#pragma unroll
    for (int i = 0; i < 4; ++i) {
      int ra = wm + i * 16 + l15, rb = wn + i * 16 + l15;
      af[i] = *(const bf16x8*)(As + (ra * 4 + (quad ^ ((ra >> 1) & 3))) * 8);
      bb[i] = *(const bf16x8*)(Bs + (rb * 4 + (quad ^ ((rb >> 1) & 3))) * 8);
    }
#pragma unroll
    for (int mi = 0; mi < 4; ++mi)
#pragma unroll
      for (int ni = 0; ni < 4; ++ni)
        acc[mi][ni] = MFMA16(af[mi], bb[ni], acc[mi][ni]);
    __syncthreads();
  }
  const float scale = (z == 0) ? QSCALE : 1.0f;
#pragma unroll
  for (int mi = 0; mi < 4; ++mi)
#pragma unroll
    for (int ni = 0; ni < 4; ++ni) {
      int row = m0 + wm + mi * 16 + quad * 4;
      int col = n0 + wn + ni * 16 + l15;
      float bz = bias[col];
      if (z == 2) {
        int b_ = row >> 11, l = row & 2047;
        int hh = l >> 7;
        int i0 = (l & 127) * 16 + (col >> 6);
        int d  = col & 63;
        bf16* dst = C + (size_t)(b_ * 16 + hh) * 131072;
#pragma unroll
        for (int r = 0; r < 4; ++r) {
          int iK = i0 + 16 * r;
          dst[((size_t)(iK >> 2) * 64 + d) * 4 + (iK & 3)] = (bf16)(acc[mi][ni][r] + bz);
        }
      } else {
#pragma unroll
        for (int r = 0; r < 4; ++r)
          C[(size_t)(row + r) * 1024 + col] = (bf16)((acc[mi][ni][r] + bz) * scale);
      }
    }
}

// ---------- output GEMM: 64x128 tile, fp32 out + bias ----------
__global__ __launch_bounds__(256) void k_gemmo(const bf16* __restrict__ A,
                                               const bf16* __restrict__ Bt,
                                               const float* __restrict__ bias,
                                               float* __restrict__ C) {
  const int m0 = blockIdx.y * 64, n0 = blockIdx.x * 128;
  __shared__ __align__(16) bf16 As[64 * 32];
  __shared__ __align__(16) bf16 Bs[128 * 32];
  const int tid = threadIdx.x, lane = tid & 63, w = tid >> 6, quad = lane >> 4, l15 = lane & 15;
  const int wn = w * 32;
  f32x4 acc[4][2] = {};
  for (int kt = 0; kt < 32; ++kt) {
    const int kk = kt * 32;
    {
      int r = tid >> 2, c = (tid & 3) ^ ((r >> 1) & 3);
      GLOAD16(A + (size_t)(m0 + r) * 1024 + kk + c * 8, As + tid * 8);
    }
#pragma unroll
    for (int i = 0; i < 2; ++i) {
      int s = tid + i * 256;
      int r = s >> 2, c = (s & 3) ^ ((r >> 1) & 3);
      GLOAD16(Bt + (size_t)(n0 + r) * 1024 + kk + c * 8, Bs + s * 8);
    }
    __syncthreads();
    bf16x8 af[4], bb[2];
#pragma unroll
    for (int i = 0; i < 4; ++i) {
      int ra = i * 16 + l15;
      af[i] = *(const bf16x8*)(As + (ra * 4 + (quad ^ ((ra >> 1) & 3))) * 8);
    }
#pragma unroll
    for (int i = 0; i < 2; ++i) {
      int rb = wn + i * 16 + l15;
      bb[i] = *(const bf16x8*)(Bs + (rb * 4 + (quad ^ ((rb >> 1) & 3))) * 8);
    }
#pragma unroll
    for (int mi = 0; mi < 4; ++mi)
#pragma unroll
      for (int ni = 0; ni < 2; ++ni)
        acc[mi][ni] = MFMA16(af[mi], bb[ni], acc[mi][ni]);
    __syncthreads();
  }
#pragma unroll
  for (int mi = 0; mi < 4; ++mi)
#pragma unroll
    for (int ni = 0; ni < 2; ++ni) {
      int row = m0 + mi * 16 + quad * 4;
      int col = n0 + wn + ni * 16 + l15;
      float bz = bias[col];
#pragma unroll
      for (int r = 0; r < 4; ++r)
        C[(size_t)(row + r) * 1024 + col] = acc[mi][ni][r] + bz;
    }
}

// ---------- flash attention: NO LDS, NO barriers. q-tile 64, all operands
// direct from global (K via L1 broadcast across waves, V pre-tiled coalesced,
// mask 8B/lane). Transposed-scores, P in registers, lsum via ones-MFMA. ----------
__global__ __launch_bounds__(256) void k_flash(const bf16* __restrict__ Qp,
                                               const bf16* __restrict__ Kp,
                                               const bf16* __restrict__ Vtp,
                                               const ull* __restrict__ mb,
                                               bf16* __restrict__ ctx) {
  const int b = blockIdx.z, h = blockIdx.y, q0 = blockIdx.x * 64;
  const size_t HEAD = 131072;
  const bf16* Q  = Qp  + ((size_t)b * NH_ + h) * HEAD;  // pre-scaled by QSCALE
  const bf16* K  = Kp  + ((size_t)b * NH_ + h) * HEAD;  // row-major [key][d]
  const bf16* Vt = Vtp + ((size_t)b * NH_ + h) * HEAD;  // pre-tiled [i>>2][d][i&3]

  const int tid = threadIdx.x, lane = tid & 63, w = tid >> 6, quad = lane >> 4, l15 = lane & 15;

  // Q fragments (B-operand: n=q=l15, k=ks*32+quad*8+j)
  bf16x8 qf[2];
#pragma unroll
  for (int ks = 0; ks < 2; ++ks)
    qf[ks] = *(const bf16x8*)(Q + (size_t)(q0 + w * 16 + l15) * 64 + ks * 32 + quad * 8);

  // per-lane mask row pointer (q = w*16 + l15)
  const ull* mlane = mb + (size_t)b * L_ * 32 + (size_t)(q0 + w * 16 + l15) * 32;

  f32x4 accO[4] = {};
  f32x4 accL = {};
  const s16x4 onesf = {0x3F80, 0x3F80, 0x3F80, 0x3F80};  // bf16 1.0 x4

  for (int kt = 0; kt < 32; ++kt) {
    // St[kb] = K Q^T  (A=K frag direct from global: m=key=kb*16+l15, k=ks*32+quad*8+j)
    f32x4 st[4] = {};
#pragma unroll
    for (int ks = 0; ks < 2; ++ks)
#pragma unroll
      for (int kb = 0; kb < 4; ++kb) {
        bf16x8 kf = *(const bf16x8*)(K + (size_t)(kt * 64 + kb * 16 + l15) * 64 + ks * 32 + quad * 8);
        st[kb] = MFMA16(kf, qf[ks], st[kb]);
      }

    // mask + exp2 + pack to PV A-fragments
    const ull word = mlane[kt];
    s16x4 pf[4];
#pragma unroll
    for (int kb = 0; kb < 4; ++kb) {
      const unsigned nib = (unsigned)(word >> (kb * 16 + quad * 4)) & 0xFu;
      float p0 = (nib & 1u) ? __builtin_amdgcn_exp2f(st[kb][0]) : 0.f;
      float p1 = (nib & 2u) ? __builtin_amdgcn_exp2f(st[kb][1]) : 0.f;
      float p2 = (nib & 4u) ? __builtin_amdgcn_exp2f(st[kb][2]) : 0.f;
      float p3 = (nib & 8u) ? __builtin_amdgcn_exp2f(st[kb][3]) : 0.f;
      bf16x4 pb = {(bf16)p0, (bf16)p1, (bf16)p2, (bf16)p3};
      pf[kb] = __builtin_bit_cast(s16x4, pb);
    }

    // lsum via ones-MFMA (accL rows == accO rows)
#pragma unroll
    for (int kb = 0; kb < 4; ++kb)
      accL = MFMA16K16(pf[kb], onesf, accL);

    // O += P V  (B=V frag direct from pre-tiled global: k=quad*4+j, n=d=db*16+l15)
#pragma unroll
    for (int kb = 0; kb < 4; ++kb)
#pragma unroll
      for (int db = 0; db < 4; ++db) {
        s16x4 vf = *(const s16x4*)(Vt + (size_t)kt * 4096 +
                                   ((size_t)((kb * 4 + quad) * 64 + db * 16 + l15)) * 4);
        accO[db] = MFMA16K16(pf[kb], vf, accO[db]);
      }
  }

  // epilogue: accL[r] = lsum for q=quad*4+r (uniform over l15) — no shuffles
  float rl[4];
#pragma unroll
  for (int r = 0; r < 4; ++r) rl[r] = 1.0f / accL[r];
#pragma unroll
  for (int db = 0; db < 4; ++db) {
    const int col = h * 64 + db * 16 + l15;
#pragma unroll
    for (int r = 0; r < 4; ++r) {
      const int rowg = q0 + w * 16 + quad * 4 + r;
      ctx[((size_t)b * L_ + rowg) * 1024 + col] = (bf16)(accO[db][r] * rl[r]);
    }
  }
}

extern "C" void kernel_launch(void* const* d_in, const int* in_sizes, int n_in,
                              void* d_out, int out_size, void* d_ws, size_t ws_size,
                              hipStream_t stream) {
  (void)in_sizes; (void)n_in; (void)out_size; (void)ws_size;
  const float* q    = (const float*)d_in[0];
  const float* k    = (const float*)d_in[1];
  const float* v    = (const float*)d_in[2];
  const int*   mask = (const int*)d_in[3];
  const float* Wq = (const float*)d_in[4];
  const float* bq = (const float*)d_in[5];
  const float* Wk = (const float*)d_in[6];
  const float* bk = (const float*)d_in[7];
  const float* Wv = (const float*)d_in[8];
  const float* bv = (const float*)d_in[9];
  const float* Wo = (const float*)d_in[10];
  const float* bo = (const float*)d_in[11];
  float* out = (float*)d_out;

  char* ws = (char*)d_ws;
  const size_t SX = (size_t)4096 * 1024 * 2;  // 8 MB
  const size_t SW = (size_t)1024 * 1024 * 2;  // 2 MB
  bf16* X   = (bf16*)(ws);                    // Xq|Xk|Xv
  bf16* Wt  = (bf16*)(ws + 3 * SX);           // Wqt|Wkt|Wvt|Wot
  bf16* QKV = (bf16*)(ws + 3 * SX + 4 * SW);  // Qp|Kp|Vt(pre-tiled)
  bf16* Qp  = QKV;
  bf16* Kp  = QKV + 4194304;
  bf16* Vtp = QKV + 2 * 4194304;
  bf16* Ctx = (bf16*)(ws + 6 * SX + 4 * SW);
  ull* mbits = (ull*)(ws + 7 * SX + 4 * SW);

  dim3 blk(256);
  k_prep<<<49152, blk, 0, stream>>>(q, k, v, mask, Wq, Wk, Wv, Wo, X, Wt, mbits);

  k_gemm3<<<dim3(8, 32, 3), blk, 0, stream>>>(X, Wt, bq, bk, bv, QKV);

  k_flash<<<dim3(32, NH_, B_), blk, 0, stream>>>(Qp, Kp, Vtp, mbits, Ctx);

  k_gemmo<<<dim3(8, 64), blk, 0, stream>>>(Ctx, Wt + 3 * 1048576, bo, out);
}

// Round 7
// 295.021 us; speedup vs baseline: 1.3408x; 1.3408x over previous
//
#include <hip/hip_runtime.h>
#include <stdint.h>

typedef __bf16 bf16;
typedef __bf16 bf16x8 __attribute__((ext_vector_type(8)));
typedef __bf16 bf16x4 __attribute__((ext_vector_type(4)));
typedef float  f32x4  __attribute__((ext_vector_type(4)));
typedef short  s16x4  __attribute__((ext_vector_type(4)));
typedef unsigned long long ull;

#define GLOAD16(gptr, lptr)                                                     \
  __builtin_amdgcn_global_load_lds(                                             \
      (const __attribute__((address_space(1))) void*)(gptr),                    \
      (__attribute__((address_space(3))) void*)(lptr), 16, 0, 0)

#define MFMA16(a, b, c) __builtin_amdgcn_mfma_f32_16x16x32_bf16((a), (b), (c), 0, 0, 0)
#define MFMA16K16(a, b, c) __builtin_amdgcn_mfma_f32_16x16x16bf16_1k((a), (b), (c), 0, 0, 0)

static constexpr int B_ = 2, L_ = 2048, NH_ = 16, DH_ = 64;
static constexpr float QSCALE = 0.18033688011112042f;  // 0.125 * log2(e)

// ---------- fused prep: maskbits | fp32->bf16 cvt | weight transpose ----------
__global__ __launch_bounds__(256) void k_prep(const float* __restrict__ q,
                                              const float* __restrict__ k,
                                              const float* __restrict__ v,
                                              const int* __restrict__ mask,
                                              const float* __restrict__ wq,
                                              const float* __restrict__ wk,
                                              const float* __restrict__ wv,
                                              const float* __restrict__ wo,
                                              bf16* __restrict__ X,
                                              bf16* __restrict__ Wt,
                                              ull* __restrict__ mb) {
  __shared__ float t[32][33];
  const int bid = blockIdx.x, tid = threadIdx.x;
  if (bid < 32768) {  // mask int32 -> packed bits
    int tt = bid * 256 + tid;
    ull bal = __ballot(mask[tt] != 0);
    if ((tid & 63) == 0) mb[tt >> 6] = bal;
  } else if (bid < 45056) {  // fp32 -> bf16 x4
    int u = bid - 32768;
    int z = u >> 12, x = u & 4095;
    const float* in = z == 0 ? q : (z == 1 ? k : v);
    bf16* out = X + (size_t)z * 4194304;
    int i = x * 256 + tid;
    const float4 f = ((const float4*)in)[i];
    bf16x4 o = {(bf16)f.x, (bf16)f.y, (bf16)f.z, (bf16)f.w};
    ((bf16x4*)out)[i] = o;
  } else {  // weight fp32 KxN -> bf16 NxK
    int u = bid - 45056;
    int z = u >> 10, rem = u & 1023;
    const float* in = z == 0 ? wq : (z == 1 ? wk : (z == 2 ? wv : wo));
    bf16* out = Wt + (size_t)z * 1048576;
    int bx = (rem & 31) * 32, by = (rem >> 5) * 32;
    int x = tid & 31, y = tid >> 5;
#pragma unroll
    for (int r = 0; r < 4; ++r)
      t[y + r * 8][x] = in[(size_t)(by + y + r * 8) * 1024 + bx + x];
    __syncthreads();
#pragma unroll
    for (int r = 0; r < 4; ++r)
      out[(size_t)(bx + y + r * 8) * 1024 + by + x] = (bf16)t[x][y + r * 8];
  }
}

// ---------- batched 3-proj GEMM: 128x128 tile, BK=32 ----------
// z=0: Q scaled by QSCALE. z=2: V pre-tiled per raw-view head (faithful-bug reshape):
//   h = l>>7, i = (l&127)*16 + (col>>6), d = col&63; Vt[bh][((i>>2)*64 + d)*4 + (i&3)]
__global__ __launch_bounds__(256) void k_gemm3(const bf16* __restrict__ Xb,
                                               const bf16* __restrict__ Wb,
                                               const float* __restrict__ b0,
                                               const float* __restrict__ b1,
                                               const float* __restrict__ b2,
                                               bf16* __restrict__ Ob) {
  const int z = blockIdx.z;
  const bf16* A  = Xb + (size_t)z * 4194304;
  const bf16* Bt = Wb + (size_t)z * 1048576;
  const float* bias = z == 0 ? b0 : (z == 1 ? b1 : b2);
  bf16* C = Ob + (size_t)z * 4194304;
  const int m0 = blockIdx.y * 128, n0 = blockIdx.x * 128;
  __shared__ __align__(16) bf16 As[128 * 32];  // slot(r,c) = r*4 + (c ^ ((r>>1)&3))
  __shared__ __align__(16) bf16 Bs[128 * 32];
  const int tid = threadIdx.x, lane = tid & 63, w = tid >> 6, quad = lane >> 4, l15 = lane & 15;
  const int wm = (w & 1) * 64, wn = (w >> 1) * 64;
  f32x4 acc[4][4] = {};
  for (int kt = 0; kt < 32; ++kt) {
    const int kk = kt * 32;
#pragma unroll
    for (int i = 0; i < 2; ++i) {
      int s = tid + i * 256;
      int r = s >> 2, c = (s & 3) ^ ((r >> 1) & 3);
      GLOAD16(A + (size_t)(m0 + r) * 1024 + kk + c * 8, As + s * 8);
      GLOAD16(Bt + (size_t)(n0 + r) * 1024 + kk + c * 8, Bs + s * 8);
    }
    __syncthreads();
    bf16x8 af[4], bb[4];
#pragma unroll
    for (int i = 0; i < 4; ++i) {
      int ra = wm + i * 16 + l15, rb = wn + i * 16 + l15;
      af[i] = *(const bf16x8*)(As + (ra * 4 + (quad ^ ((ra >> 1) & 3))) * 8);
      bb[i] = *(const bf16x8*)(Bs + (rb * 4 + (quad ^ ((rb >> 1) & 3))) * 8);
    }
#pragma unroll
    for (int mi = 0; mi < 4; ++mi)
#pragma unroll
      for (int ni = 0; ni < 4; ++ni)
        acc[mi][ni] = MFMA16(af[mi], bb[ni], acc[mi][ni]);
    __syncthreads();
  }
  const float scale = (z == 0) ? QSCALE : 1.0f;
#pragma unroll
  for (int mi = 0; mi < 4; ++mi)
#pragma unroll
    for (int ni = 0; ni < 4; ++ni) {
      int row = m0 + wm + mi * 16 + quad * 4;
      int col = n0 + wn + ni * 16 + l15;
      float bz = bias[col];
      if (z == 2) {
        int b_ = row >> 11, l = row & 2047;
        int hh = l >> 7;
        int i0 = (l & 127) * 16 + (col >> 6);
        int d  = col & 63;
        bf16* dst = C + (size_t)(b_ * 16 + hh) * 131072;
#pragma unroll
        for (int r = 0; r < 4; ++r) {
          int iK = i0 + 16 * r;
          dst[((size_t)(iK >> 2) * 64 + d) * 4 + (iK & 3)] = (bf16)(acc[mi][ni][r] + bz);
        }
      } else {
#pragma unroll
        for (int r = 0; r < 4; ++r)
          C[(size_t)(row + r) * 1024 + col] = (bf16)((acc[mi][ni][r] + bz) * scale);
      }
    }
}

// ---------- output GEMM: 64x128 tile, fp32 out + bias ----------
__global__ __launch_bounds__(256) void k_gemmo(const bf16* __restrict__ A,
                                               const bf16* __restrict__ Bt,
                                               const float* __restrict__ bias,
                                               float* __restrict__ C) {
  const int m0 = blockIdx.y * 64, n0 = blockIdx.x * 128;
  __shared__ __align__(16) bf16 As[64 * 32];
  __shared__ __align__(16) bf16 Bs[128 * 32];
  const int tid = threadIdx.x, lane = tid & 63, w = tid >> 6, quad = lane >> 4, l15 = lane & 15;
  const int wn = w * 32;
  f32x4 acc[4][2] = {};
  for (int kt = 0; kt < 32; ++kt) {
    const int kk = kt * 32;
    {
      int r = tid >> 2, c = (tid & 3) ^ ((r >> 1) & 3);
      GLOAD16(A + (size_t)(m0 + r) * 1024 + kk + c * 8, As + tid * 8);
    }
#pragma unroll
    for (int i = 0; i < 2; ++i) {
      int s = tid + i * 256;
      int r = s >> 2, c = (s & 3) ^ ((r >> 1) & 3);
      GLOAD16(Bt + (size_t)(n0 + r) * 1024 + kk + c * 8, Bs + s * 8);
    }
    __syncthreads();
    bf16x8 af[4], bb[2];
#pragma unroll
    for (int i = 0; i < 4; ++i) {
      int ra = i * 16 + l15;
      af[i] = *(const bf16x8*)(As + (ra * 4 + (quad ^ ((ra >> 1) & 3))) * 8);
    }
#pragma unroll
    for (int i = 0; i < 2; ++i) {
      int rb = wn + i * 16 + l15;
      bb[i] = *(const bf16x8*)(Bs + (rb * 4 + (quad ^ ((rb >> 1) & 3))) * 8);
    }
#pragma unroll
    for (int mi = 0; mi < 4; ++mi)
#pragma unroll
      for (int ni = 0; ni < 2; ++ni)
        acc[mi][ni] = MFMA16(af[mi], bb[ni], acc[mi][ni]);
    __syncthreads();
  }
#pragma unroll
  for (int mi = 0; mi < 4; ++mi)
#pragma unroll
    for (int ni = 0; ni < 2; ++ni) {
      int row = m0 + mi * 16 + quad * 4;
      int col = n0 + wn + ni * 16 + l15;
      float bz = bias[col];
#pragma unroll
      for (int r = 0; r < 4; ++r)
        C[(size_t)(row + r) * 1024 + col] = acc[mi][ni][r] + bz;
    }
}

// ---------- flash attention: q-tile 128; K+mask LDS dbuf (R4), V direct-global,
// transposed-scores, P in registers, lsum via ones-MFMA ----------
__global__ __launch_bounds__(256) void k_flash(const bf16* __restrict__ Qp,
                                               const bf16* __restrict__ Kp,
                                               const bf16* __restrict__ Vtp,
                                               const ull* __restrict__ mb,
                                               bf16* __restrict__ ctx) {
  const int b = blockIdx.z, h = blockIdx.y, q0 = blockIdx.x * 128;
  const size_t HEAD = 131072;
  const bf16* Q  = Qp  + ((size_t)b * NH_ + h) * HEAD;  // pre-scaled by QSCALE
  const bf16* K  = Kp  + ((size_t)b * NH_ + h) * HEAD;  // row-major [key][d]
  const bf16* Vt = Vtp + ((size_t)b * NH_ + h) * HEAD;  // pre-tiled [i>>2][d][i&3]
  const ull* mrow = mb + (size_t)b * L_ * 32;

  __shared__ __align__(16) bf16 Ks[2][64 * 64];  // slot(key,c) = key*8 + (c ^ (key&7))
  __shared__ __align__(16) ull  Ms[2][256];      // [buf][row*2 + parity]

  const int tid = threadIdx.x, lane = tid & 63, w = tid >> 6, quad = lane >> 4, l15 = lane & 15;

  // Q fragments (B-operand: n=q=l15, k=ks*32+quad*8+j) straight from global
  bf16x8 qf[2][2];
#pragma unroll
  for (int qb = 0; qb < 2; ++qb)
#pragma unroll
    for (int ks = 0; ks < 2; ++ks)
      qf[qb][ks] = *(const bf16x8*)(Q + (size_t)(q0 + w * 32 + qb * 16 + l15) * 64 + ks * 32 + quad * 8);

  // initial staging: kt=0 K, mask word pair (0,1)
#pragma unroll
  for (int i = 0; i < 2; ++i) {
    int s = tid + i * 256;
    int key = s >> 3, c = (s & 7) ^ (key & 7);
    GLOAD16(K + (size_t)key * 64 + c * 8, Ks[0] + s * 8);
  }
  if (w < 2) {
    int r = w * 64 + lane;
    GLOAD16(mrow + (size_t)(q0 + r) * 32, (bf16*)&Ms[0][0] + r * 8);
  }
  __syncthreads();

  f32x4 accO[2][4] = {};
  f32x4 accL[2] = {};
  const s16x4 onesf = {0x3F80, 0x3F80, 0x3F80, 0x3F80};  // bf16 1.0 x4

  for (int kt = 0; kt < 32; ++kt) {
    const int cur = kt & 1;
    // prefetch next K (+mask every other kt) into the other LDS buffer
    if (kt + 1 < 32) {
      const int nxt = cur ^ 1;
#pragma unroll
      for (int i = 0; i < 2; ++i) {
        int s = tid + i * 256;
        int key = s >> 3, c = (s & 7) ^ (key & 7);
        GLOAD16(K + (size_t)((kt + 1) * 64 + key) * 64 + c * 8, Ks[nxt] + s * 8);
      }
      if ((kt & 1) && w < 2) {
        int r = w * 64 + lane;
        GLOAD16(mrow + (size_t)(q0 + r) * 32 + (kt + 1),
                (bf16*)&Ms[((kt + 1) >> 1) & 1][0] + r * 8);
      }
    }

    // St[kb][qb] = K Q^T  (C-layout: col=q=l15, row=key=quad*4+reg)
    f32x4 st[4][2] = {};
#pragma unroll
    for (int ks = 0; ks < 2; ++ks)
#pragma unroll
      for (int kb = 0; kb < 4; ++kb) {
        int key = kb * 16 + l15;
        bf16x8 kf = *(const bf16x8*)(Ks[cur] + (key * 8 + ((ks * 4 + quad) ^ (key & 7))) * 8);
        st[kb][0] = MFMA16(kf, qf[0][ks], st[kb][0]);
        st[kb][1] = MFMA16(kf, qf[1][ks], st[kb][1]);
      }

    // mask + exp2 + pack to PV A-fragments
    const ull* Mcur = Ms[(kt >> 1) & 1];
    const ull word0 = Mcur[(w * 32 + l15) * 2 + cur];
    const ull word1 = Mcur[(w * 32 + 16 + l15) * 2 + cur];
    s16x4 pf[4][2];
#pragma unroll
    for (int kb = 0; kb < 4; ++kb)
#pragma unroll
      for (int qb = 0; qb < 2; ++qb) {
        const unsigned nib = (unsigned)((qb ? word1 : word0) >> (kb * 16 + quad * 4)) & 0xFu;
        float p0 = (nib & 1u) ? __builtin_amdgcn_exp2f(st[kb][qb][0]) : 0.f;
        float p1 = (nib & 2u) ? __builtin_amdgcn_exp2f(st[kb][qb][1]) : 0.f;
        float p2 = (nib & 4u) ? __builtin_amdgcn_exp2f(st[kb][qb][2]) : 0.f;
        float p3 = (nib & 8u) ? __builtin_amdgcn_exp2f(st[kb][qb][3]) : 0.f;
        bf16x4 pb = {(bf16)p0, (bf16)p1, (bf16)p2, (bf16)p3};
        pf[kb][qb] = __builtin_bit_cast(s16x4, pb);
      }

    // lsum via ones-MFMA (accL rows == accO rows)
#pragma unroll
    for (int kb = 0; kb < 4; ++kb) {
      accL[0] = MFMA16K16(pf[kb][0], onesf, accL[0]);
      accL[1] = MFMA16K16(pf[kb][1], onesf, accL[1]);
    }

    // O += P V  (B=V frag direct from pre-tiled global: k=quad*4+j, n=d=db*16+l15;
    //  loads are independent — issue early, reused across both qb)
#pragma unroll
    for (int kb = 0; kb < 4; ++kb) {
      s16x4 vf[4];
#pragma unroll
      for (int db = 0; db < 4; ++db)
        vf[db] = *(const s16x4*)(Vt + (size_t)kt * 4096 +
                                 ((size_t)((kb * 4 + quad) * 64 + db * 16 + l15)) * 4);
#pragma unroll
      for (int db = 0; db < 4; ++db) {
        accO[0][db] = MFMA16K16(pf[kb][0], vf[db], accO[0][db]);
        accO[1][db] = MFMA16K16(pf[kb][1], vf[db], accO[1][db]);
      }
    }
    __syncthreads();
  }

  // epilogue: accL[qb][r] = lsum for q = w*32+qb*16+quad*4+r — no shuffles
#pragma unroll
  for (int qb = 0; qb < 2; ++qb) {
    float rl[4];
#pragma unroll
    for (int r = 0; r < 4; ++r) rl[r] = 1.0f / accL[qb][r];
#pragma unroll
    for (int db = 0; db < 4; ++db) {
      const int col = h * 64 + db * 16 + l15;
#pragma unroll
      for (int r = 0; r < 4; ++r) {
        const int rowg = q0 + w * 32 + qb * 16 + quad * 4 + r;
        ctx[((size_t)b * L_ + rowg) * 1024 + col] = (bf16)(accO[qb][db][r] * rl[r]);
      }
    }
  }
}

extern "C" void kernel_launch(void* const* d_in, const int* in_sizes, int n_in,
                              void* d_out, int out_size, void* d_ws, size_t ws_size,
                              hipStream_t stream) {
  (void)in_sizes; (void)n_in; (void)out_size; (void)ws_size;
  const float* q    = (const float*)d_in[0];
  const float* k    = (const float*)d_in[1];
  const float* v    = (const float*)d_in[2];
  const int*   mask = (const int*)d_in[3];
  const float* Wq = (const float*)d_in[4];
  const float* bq = (const float*)d_in[5];
  const float* Wk = (const float*)d_in[6];
  const float* bk = (const float*)d_in[7];
  const float* Wv = (const float*)d_in[8];
  const float* bv = (const float*)d_in[9];
  const float* Wo = (const float*)d_in[10];
  const float* bo = (const float*)d_in[11];
  float* out = (float*)d_out;

  char* ws = (char*)d_ws;
  const size_t SX = (size_t)4096 * 1024 * 2;  // 8 MB
  const size_t SW = (size_t)1024 * 1024 * 2;  // 2 MB
  bf16* X   = (bf16*)(ws);                    // Xq|Xk|Xv
  bf16* Wt  = (bf16*)(ws + 3 * SX);           // Wqt|Wkt|Wvt|Wot
  bf16* QKV = (bf16*)(ws + 3 * SX + 4 * SW);  // Qp|Kp|Vt(pre-tiled)
  bf16* Qp  = QKV;
  bf16* Kp  = QKV + 4194304;
  bf16* Vtp = QKV + 2 * 4194304;
  bf16* Ctx = (bf16*)(ws + 6 * SX + 4 * SW);
  ull* mbits = (ull*)(ws + 7 * SX + 4 * SW);

  dim3 blk(256);
  k_prep<<<49152, blk, 0, stream>>>(q, k, v, mask, Wq, Wk, Wv, Wo, X, Wt, mbits);

  k_gemm3<<<dim3(8, 32, 3), blk, 0, stream>>>(X, Wt, bq, bk, bv, QKV);

  k_flash<<<dim3(16, NH_, B_), blk, 0, stream>>>(Qp, Kp, Vtp, mbits, Ctx);

  k_gemmo<<<dim3(8, 64), blk, 0, stream>>>(Ctx, Wt + 3 * 1048576, bo, out);
}

// Round 8
// 273.944 us; speedup vs baseline: 1.4440x; 1.0769x over previous
//
#include <hip/hip_runtime.h>
#include <stdint.h>

typedef __bf16 bf16;
typedef __bf16 bf16x8 __attribute__((ext_vector_type(8)));
typedef __bf16 bf16x4 __attribute__((ext_vector_type(4)));
typedef float  f32x4  __attribute__((ext_vector_type(4)));
typedef short  s16x4  __attribute__((ext_vector_type(4)));
typedef unsigned long long ull;

#define GLOAD16(gptr, lptr)                                                     \
  __builtin_amdgcn_global_load_lds(                                             \
      (const __attribute__((address_space(1))) void*)(gptr),                    \
      (__attribute__((address_space(3))) void*)(lptr), 16, 0, 0)

#define MFMA16(a, b, c) __builtin_amdgcn_mfma_f32_16x16x32_bf16((a), (b), (c), 0, 0, 0)
#define MFMA16K16(a, b, c) __builtin_amdgcn_mfma_f32_16x16x16bf16_1k((a), (b), (c), 0, 0, 0)

static constexpr int B_ = 2, L_ = 2048, NH_ = 16, DH_ = 64;
static constexpr float QSCALE = 0.18033688011112042f;  // 0.125 * log2(e)

// ---------- fused prep: maskbits | fp32->bf16 cvt | weight transpose ----------
__global__ __launch_bounds__(256) void k_prep(const float* __restrict__ q,
                                              const float* __restrict__ k,
                                              const float* __restrict__ v,
                                              const int* __restrict__ mask,
                                              const float* __restrict__ wq,
                                              const float* __restrict__ wk,
                                              const float* __restrict__ wv,
                                              const float* __restrict__ wo,
                                              bf16* __restrict__ X,
                                              bf16* __restrict__ Wt,
                                              ull* __restrict__ mb) {
  __shared__ float t[32][33];
  const int bid = blockIdx.x, tid = threadIdx.x;
  if (bid < 32768) {  // mask int32 -> packed bits
    int tt = bid * 256 + tid;
    ull bal = __ballot(mask[tt] != 0);
    if ((tid & 63) == 0) mb[tt >> 6] = bal;
  } else if (bid < 45056) {  // fp32 -> bf16 x4
    int u = bid - 32768;
    int z = u >> 12, x = u & 4095;
    const float* in = z == 0 ? q : (z == 1 ? k : v);
    bf16* out = X + (size_t)z * 4194304;
    int i = x * 256 + tid;
    const float4 f = ((const float4*)in)[i];
    bf16x4 o = {(bf16)f.x, (bf16)f.y, (bf16)f.z, (bf16)f.w};
    ((bf16x4*)out)[i] = o;
  } else {  // weight fp32 KxN -> bf16 NxK
    int u = bid - 45056;
    int z = u >> 10, rem = u & 1023;
    const float* in = z == 0 ? wq : (z == 1 ? wk : (z == 2 ? wv : wo));
    bf16* out = Wt + (size_t)z * 1048576;
    int bx = (rem & 31) * 32, by = (rem >> 5) * 32;
    int x = tid & 31, y = tid >> 5;
#pragma unroll
    for (int r = 0; r < 4; ++r)
      t[y + r * 8][x] = in[(size_t)(by + y + r * 8) * 1024 + bx + x];
    __syncthreads();
#pragma unroll
    for (int r = 0; r < 4; ++r)
      out[(size_t)(bx + y + r * 8) * 1024 + by + x] = (bf16)t[x][y + r * 8];
  }
}

// ---------- batched 3-proj GEMM: 128x128 tile, BK=32 ----------
// z=0: Q scaled by QSCALE. z=2: V pre-tiled per raw-view head (faithful-bug reshape):
//   h = l>>7, i = (l&127)*16 + (col>>6), d = col&63; Vt[bh][((i>>2)*64 + d)*4 + (i&3)]
__global__ __launch_bounds__(256) void k_gemm3(const bf16* __restrict__ Xb,
                                               const bf16* __restrict__ Wb,
                                               const float* __restrict__ b0,
                                               const float* __restrict__ b1,
                                               const float* __restrict__ b2,
                                               bf16* __restrict__ Ob) {
  const int z = blockIdx.z;
  const bf16* A  = Xb + (size_t)z * 4194304;
  const bf16* Bt = Wb + (size_t)z * 1048576;
  const float* bias = z == 0 ? b0 : (z == 1 ? b1 : b2);
  bf16* C = Ob + (size_t)z * 4194304;
  const int m0 = blockIdx.y * 128, n0 = blockIdx.x * 128;
  __shared__ __align__(16) bf16 As[128 * 32];  // slot(r,c) = r*4 + (c ^ ((r>>1)&3))
  __shared__ __align__(16) bf16 Bs[128 * 32];
  const int tid = threadIdx.x, lane = tid & 63, w = tid >> 6, quad = lane >> 4, l15 = lane & 15;
  const int wm = (w & 1) * 64, wn = (w >> 1) * 64;
  f32x4 acc[4][4] = {};
  for (int kt = 0; kt < 32; ++kt) {
    const int kk = kt * 32;
#pragma unroll
    for (int i = 0; i < 2; ++i) {
      int s = tid + i * 256;
      int r = s >> 2, c = (s & 3) ^ ((r >> 1) & 3);
      GLOAD16(A + (size_t)(m0 + r) * 1024 + kk + c * 8, As + s * 8);
      GLOAD16(Bt + (size_t)(n0 + r) * 1024 + kk + c * 8, Bs + s * 8);
    }
    __syncthreads();
    bf16x8 af[4], bb[4];
#pragma unroll
    for (int i = 0; i < 4; ++i) {
      int ra = wm + i * 16 + l15, rb = wn + i * 16 + l15;
      af[i] = *(const bf16x8*)(As + (ra * 4 + (quad ^ ((ra >> 1) & 3))) * 8);
      bb[i] = *(const bf16x8*)(Bs + (rb * 4 + (quad ^ ((rb >> 1) & 3))) * 8);
    }
#pragma unroll
    for (int mi = 0; mi < 4; ++mi)
#pragma unroll
      for (int ni = 0; ni < 4; ++ni)
        acc[mi][ni] = MFMA16(af[mi], bb[ni], acc[mi][ni]);
    __syncthreads();
  }
  const float scale = (z == 0) ? QSCALE : 1.0f;
#pragma unroll
  for (int mi = 0; mi < 4; ++mi)
#pragma unroll
    for (int ni = 0; ni < 4; ++ni) {
      int row = m0 + wm + mi * 16 + quad * 4;
      int col = n0 + wn + ni * 16 + l15;
      float bz = bias[col];
      if (z == 2) {
        int b_ = row >> 11, l = row & 2047;
        int hh = l >> 7;
        int i0 = (l & 127) * 16 + (col >> 6);
        int d  = col & 63;
        bf16* dst = C + (size_t)(b_ * 16 + hh) * 131072;
#pragma unroll
        for (int r = 0; r < 4; ++r) {
          int iK = i0 + 16 * r;
          dst[((size_t)(iK >> 2) * 64 + d) * 4 + (iK & 3)] = (bf16)(acc[mi][ni][r] + bz);
        }
      } else {
#pragma unroll
        for (int r = 0; r < 4; ++r)
          C[(size_t)(row + r) * 1024 + col] = (bf16)((acc[mi][ni][r] + bz) * scale);
      }
    }
}

// ---------- output GEMM: 64x128 tile, fp32 out + bias ----------
__global__ __launch_bounds__(256) void k_gemmo(const bf16* __restrict__ A,
                                               const bf16* __restrict__ Bt,
                                               const float* __restrict__ bias,
                                               float* __restrict__ C) {
  const int m0 = blockIdx.y * 64, n0 = blockIdx.x * 128;
  __shared__ __align__(16) bf16 As[64 * 32];
  __shared__ __align__(16) bf16 Bs[128 * 32];
  const int tid = threadIdx.x, lane = tid & 63, w = tid >> 6, quad = lane >> 4, l15 = lane & 15;
  const int wn = w * 32;
  f32x4 acc[4][2] = {};
  for (int kt = 0; kt < 32; ++kt) {
    const int kk = kt * 32;
    {
      int r = tid >> 2, c = (tid & 3) ^ ((r >> 1) & 3);
      GLOAD16(A + (size_t)(m0 + r) * 1024 + kk + c * 8, As + tid * 8);
    }
#pragma unroll
    for (int i = 0; i < 2; ++i) {
      int s = tid + i * 256;
      int r = s >> 2, c = (s & 3) ^ ((r >> 1) & 3);
      GLOAD16(Bt + (size_t)(n0 + r) * 1024 + kk + c * 8, Bs + s * 8);
    }
    __syncthreads();
    bf16x8 af[4], bb[2];
#pragma unroll
    for (int i = 0; i < 4; ++i) {
      int ra = i * 16 + l15;
      af[i] = *(const bf16x8*)(As + (ra * 4 + (quad ^ ((ra >> 1) & 3))) * 8);
    }
#pragma unroll
    for (int i = 0; i < 2; ++i) {
      int rb = wn + i * 16 + l15;
      bb[i] = *(const bf16x8*)(Bs + (rb * 4 + (quad ^ ((rb >> 1) & 3))) * 8);
    }
#pragma unroll
    for (int mi = 0; mi < 4; ++mi)
#pragma unroll
      for (int ni = 0; ni < 2; ++ni)
        acc[mi][ni] = MFMA16(af[mi], bb[ni], acc[mi][ni]);
    __syncthreads();
  }
#pragma unroll
  for (int mi = 0; mi < 4; ++mi)
#pragma unroll
    for (int ni = 0; ni < 2; ++ni) {
      int row = m0 + mi * 16 + quad * 4;
      int col = n0 + wn + ni * 16 + l15;
      float bz = bias[col];
#pragma unroll
      for (int r = 0; r < 4; ++r)
        C[(size_t)(row + r) * 1024 + col] = acc[mi][ni][r] + bz;
    }
}

// ---------- flash attention: q-tile 128; K+V+mask LDS dbuf (R4 staging),
// transposed-scores, P in registers, lsum via ones-MFMA ----------
__global__ __launch_bounds__(256) void k_flash(const bf16* __restrict__ Qp,
                                               const bf16* __restrict__ Kp,
                                               const bf16* __restrict__ Vtp,
                                               const ull* __restrict__ mb,
                                               bf16* __restrict__ ctx) {
  const int b = blockIdx.z, h = blockIdx.y, q0 = blockIdx.x * 128;
  const size_t HEAD = 131072;
  const bf16* Q  = Qp  + ((size_t)b * NH_ + h) * HEAD;  // pre-scaled by QSCALE
  const bf16* K  = Kp  + ((size_t)b * NH_ + h) * HEAD;  // row-major [key][d]
  const bf16* Vt = Vtp + ((size_t)b * NH_ + h) * HEAD;  // pre-tiled [i>>2][d][i&3]
  const ull* mrow = mb + (size_t)b * L_ * 32;

  __shared__ __align__(16) bf16 Ks[2][64 * 64];  // slot(key,c) = key*8 + (c ^ (key&7))
  __shared__ __align__(16) bf16 Vs[2][64 * 64];  // straight copy of pre-tiled chunk
  __shared__ __align__(16) ull  Ms[2][256];      // [buf][row*2 + parity]

  const int tid = threadIdx.x, lane = tid & 63, w = tid >> 6, quad = lane >> 4, l15 = lane & 15;

  // Q fragments (B-operand: n=q=l15, k=ks*32+quad*8+j) straight from global
  bf16x8 qf[2][2];
#pragma unroll
  for (int qb = 0; qb < 2; ++qb)
#pragma unroll
    for (int ks = 0; ks < 2; ++ks)
      qf[qb][ks] = *(const bf16x8*)(Q + (size_t)(q0 + w * 32 + qb * 16 + l15) * 64 + ks * 32 + quad * 8);

  // initial staging: kt=0 K/V, mask word pair (0,1)
#pragma unroll
  for (int i = 0; i < 2; ++i) {
    int s = tid + i * 256;
    int key = s >> 3, c = (s & 7) ^ (key & 7);
    GLOAD16(K + (size_t)key * 64 + c * 8, Ks[0] + s * 8);
    GLOAD16(Vt + (size_t)s * 8, Vs[0] + s * 8);
  }
  if (w < 2) {
    int r = w * 64 + lane;
    GLOAD16(mrow + (size_t)(q0 + r) * 32, (bf16*)&Ms[0][0] + r * 8);
  }
  __syncthreads();

  f32x4 accO[2][4] = {};
  f32x4 accL[2] = {};
  const s16x4 onesf = {0x3F80, 0x3F80, 0x3F80, 0x3F80};  // bf16 1.0 x4

  for (int kt = 0; kt < 32; ++kt) {
    const int cur = kt & 1;
    // prefetch next K/V (+mask every other kt) into the other LDS buffer
    if (kt + 1 < 32) {
      const int nxt = cur ^ 1;
#pragma unroll
      for (int i = 0; i < 2; ++i) {
        int s = tid + i * 256;
        int key = s >> 3, c = (s & 7) ^ (key & 7);
        GLOAD16(K + (size_t)((kt + 1) * 64 + key) * 64 + c * 8, Ks[nxt] + s * 8);
        GLOAD16(Vt + (size_t)(kt + 1) * 4096 + s * 8, Vs[nxt] + s * 8);
      }
      if ((kt & 1) && w < 2) {
        int r = w * 64 + lane;
        GLOAD16(mrow + (size_t)(q0 + r) * 32 + (kt + 1),
                (bf16*)&Ms[((kt + 1) >> 1) & 1][0] + r * 8);
      }
    }

    // St[kb][qb] = K Q^T  (C-layout: col=q=l15, row=key=quad*4+reg)
    f32x4 st[4][2] = {};
#pragma unroll
    for (int ks = 0; ks < 2; ++ks)
#pragma unroll
      for (int kb = 0; kb < 4; ++kb) {
        int key = kb * 16 + l15;
        bf16x8 kf = *(const bf16x8*)(Ks[cur] + (key * 8 + ((ks * 4 + quad) ^ (key & 7))) * 8);
        st[kb][0] = MFMA16(kf, qf[0][ks], st[kb][0]);
        st[kb][1] = MFMA16(kf, qf[1][ks], st[kb][1]);
      }

    // mask + exp2 + pack to PV A-fragments
    const ull* Mcur = Ms[(kt >> 1) & 1];
    const ull word0 = Mcur[(w * 32 + l15) * 2 + cur];
    const ull word1 = Mcur[(w * 32 + 16 + l15) * 2 + cur];
    s16x4 pf[4][2];
#pragma unroll
    for (int kb = 0; kb < 4; ++kb)
#pragma unroll
      for (int qb = 0; qb < 2; ++qb) {
        const unsigned nib = (unsigned)((qb ? word1 : word0) >> (kb * 16 + quad * 4)) & 0xFu;
        float p0 = (nib & 1u) ? __builtin_amdgcn_exp2f(st[kb][qb][0]) : 0.f;
        float p1 = (nib & 2u) ? __builtin_amdgcn_exp2f(st[kb][qb][1]) : 0.f;
        float p2 = (nib & 4u) ? __builtin_amdgcn_exp2f(st[kb][qb][2]) : 0.f;
        float p3 = (nib & 8u) ? __builtin_amdgcn_exp2f(st[kb][qb][3]) : 0.f;
        bf16x4 pb = {(bf16)p0, (bf16)p1, (bf16)p2, (bf16)p3};
        pf[kb][qb] = __builtin_bit_cast(s16x4, pb);
      }

    // lsum via ones-MFMA (accL rows == accO rows)
#pragma unroll
    for (int kb = 0; kb < 4; ++kb) {
      accL[0] = MFMA16K16(pf[kb][0], onesf, accL[0]);
      accL[1] = MFMA16K16(pf[kb][1], onesf, accL[1]);
    }

    // O += P V  (A=P regs [m=q=l15, k=quad*4+j], B=V frag [k=quad*4+j, n=d=db*16+l15])
#pragma unroll
    for (int kb = 0; kb < 4; ++kb)
#pragma unroll
      for (int db = 0; db < 4; ++db) {
        s16x4 vf = *(const s16x4*)(Vs[cur] + ((size_t)((kb * 4 + quad) * 64 + db * 16 + l15)) * 4);
        accO[0][db] = MFMA16K16(pf[kb][0], vf, accO[0][db]);
        accO[1][db] = MFMA16K16(pf[kb][1], vf, accO[1][db]);
      }
    __syncthreads();
  }

  // epilogue: accL[qb][r] = lsum for q = w*32+qb*16+quad*4+r — no shuffles
#pragma unroll
  for (int qb = 0; qb < 2; ++qb) {
    float rl[4];
#pragma unroll
    for (int r = 0; r < 4; ++r) rl[r] = 1.0f / accL[qb][r];
#pragma unroll
    for (int db = 0; db < 4; ++db) {
      const int col = h * 64 + db * 16 + l15;
#pragma unroll
      for (int r = 0; r < 4; ++r) {
        const int rowg = q0 + w * 32 + qb * 16 + quad * 4 + r;
        ctx[((size_t)b * L_ + rowg) * 1024 + col] = (bf16)(accO[qb][db][r] * rl[r]);
      }
    }
  }
}

extern "C" void kernel_launch(void* const* d_in, const int* in_sizes, int n_in,
                              void* d_out, int out_size, void* d_ws, size_t ws_size,
                              hipStream_t stream) {
  (void)in_sizes; (void)n_in; (void)out_size; (void)ws_size;
  const float* q    = (const float*)d_in[0];
  const float* k    = (const float*)d_in[1];
  const float* v    = (const float*)d_in[2];
  const int*   mask = (const int*)d_in[3];
  const float* Wq = (const float*)d_in[4];
  const float* bq = (const float*)d_in[5];
  const float* Wk = (const float*)d_in[6];
  const float* bk = (const float*)d_in[7];
  const float* Wv = (const float*)d_in[8];
  const float* bv = (const float*)d_in[9];
  const float* Wo = (const float*)d_in[10];
  const float* bo = (const float*)d_in[11];
  float* out = (float*)d_out;

  char* ws = (char*)d_ws;
  const size_t SX = (size_t)4096 * 1024 * 2;  // 8 MB
  const size_t SW = (size_t)1024 * 1024 * 2;  // 2 MB
  bf16* X   = (bf16*)(ws);                    // Xq|Xk|Xv
  bf16* Wt  = (bf16*)(ws + 3 * SX);           // Wqt|Wkt|Wvt|Wot
  bf16* QKV = (bf16*)(ws + 3 * SX + 4 * SW);  // Qp|Kp|Vt(pre-tiled)
  bf16* Qp  = QKV;
  bf16* Kp  = QKV + 4194304;
  bf16* Vtp = QKV + 2 * 4194304;
  bf16* Ctx = (bf16*)(ws + 6 * SX + 4 * SW);
  ull* mbits = (ull*)(ws + 7 * SX + 4 * SW);

  dim3 blk(256);
  k_prep<<<49152, blk, 0, stream>>>(q, k, v, mask, Wq, Wk, Wv, Wo, X, Wt, mbits);

  k_gemm3<<<dim3(8, 32, 3), blk, 0, stream>>>(X, Wt, bq, bk, bv, QKV);

  k_flash<<<dim3(16, NH_, B_), blk, 0, stream>>>(Qp, Kp, Vtp, mbits, Ctx);

  k_gemmo<<<dim3(8, 64), blk, 0, stream>>>(Ctx, Wt + 3 * 1048576, bo, out);
}